// Round 6
// baseline (290.346 us; speedup 1.0000x reference)
//
#include <hip/hip_runtime.h>
#include <math.h>

// Problem constants (fixed by setup_inputs)
#define BB 8
#define TT 8
#define NN 196
#define DD 768
#define HH 12
#define HD 64
#define TN (TT * NN)   // 1568
#define MM (BB * TN)   // 12544
#define D3 (3 * DD)    // 2304

typedef _Float16 f16;
typedef _Float16 f16x8 __attribute__((ext_vector_type(8)));
typedef _Float16 f16x4 __attribute__((ext_vector_type(4)));
typedef float f32x4 __attribute__((ext_vector_type(4)));
typedef unsigned int u32;

// async global->LDS, 16B per lane; LDS dest must be wave-uniform base + lane*16
#define GLDS16(gp, lp)                                                        \
  __builtin_amdgcn_global_load_lds(                                           \
      (const __attribute__((address_space(1))) u32*)(gp),                     \
      (__attribute__((address_space(3))) u32*)(lp), 16, 0, 0)

#define MFMA16(a, b, c) __builtin_amdgcn_mfma_f32_16x16x32_f16(a, b, c, 0, 0, 0)

// ---------------------------------------------------------------------------
// fp16 NT GEMM via MFMA: C = A[M][K] @ Bt[Ncol][K]^T
// mode 0: fp32 out + bias (token-major)           -> C32
// mode 1: fp16 out scattered to qkv tile layout   -> C16
// 128x128 tile, BK=64, 256 threads (2x2 waves), 2x(4x4) of 16x16x32 MFMA.
// LDS chunk-XOR swizzle by (row&7); swizzle absorbed into global src address.
//
// XCD-partitioned 1D launch: id&7 = XCD (round-robin heuristic); each XCD
// owns the stride-8 subset of M-tiles and sweeps all N-tiles per M-tile ->
// A fetched once device-wide (disjoint M-slabs), B L2-resident per XCD.
// Grid = 8 * ceil(mTiles/8) * nTiles; overflow blocks early-return.
// ---------------------------------------------------------------------------
__global__ __launch_bounds__(256) void gemm_f16nt(
    const f16* __restrict__ A, const f16* __restrict__ Bt,
    float* __restrict__ C32, f16* __restrict__ C16, int K, int Ncol,
    const float* __restrict__ bias, int mode, int mTiles, int nTiles) {
  __shared__ f16 As[128 * 64];
  __shared__ f16 Bs[128 * 64];

  const int flat = blockIdx.x;
  const int xcd = flat & 7;
  const int j = flat >> 3;
  const int mb = xcd + 8 * (j / nTiles);
  const int nb = j % nTiles;
  if (mb >= mTiles) return;
  const int bm = mb * 128;
  const int bn = nb * 128;

  const int tid = threadIdx.x;
  const int lane = tid & 63;
  const int wave = tid >> 6;
  const int wy = wave >> 1, wx = wave & 1;

  // staging: 1024 chunks (16B) per matrix; 4 per thread.
  const f16* aP[4];
  const f16* bP[4];
#pragma unroll
  for (int it = 0; it < 4; it++) {
    int ci = tid + it * 256;
    int r = ci >> 3;
    int c = (ci & 7) ^ (r & 7);
    aP[it] = A + (size_t)(bm + r) * K + c * 8;
    bP[it] = Bt + (size_t)(bn + r) * K + c * 8;
  }

  f32x4 acc[4][4];
#pragma unroll
  for (int i = 0; i < 4; i++)
#pragma unroll
    for (int j2 = 0; j2 < 4; j2++) acc[i][j2] = (f32x4)0.0f;

  const int fr = lane & 15;
  const int q = lane >> 4;
  const int sw = fr & 7;

  for (int kt = 0; kt < K; kt += 64) {
#pragma unroll
    for (int it = 0; it < 4; it++) {
      GLDS16(aP[it] + kt, &As[(tid + it * 256) * 8]);
      GLDS16(bP[it] + kt, &Bs[(tid + it * 256) * 8]);
    }
    __syncthreads();

#pragma unroll
    for (int kk = 0; kk < 2; kk++) {
      const int lc = ((kk * 4 + q) ^ sw) * 8;
      f16x8 af[4], bf[4];
#pragma unroll
      for (int mi = 0; mi < 4; mi++)
        af[mi] = *(const f16x8*)&As[(wy * 64 + mi * 16 + fr) * 64 + lc];
#pragma unroll
      for (int ni = 0; ni < 4; ni++)
        bf[ni] = *(const f16x8*)&Bs[(wx * 64 + ni * 16 + fr) * 64 + lc];

#pragma unroll
      for (int mi = 0; mi < 4; mi++)
#pragma unroll
        for (int ni = 0; ni < 4; ni++)
          acc[mi][ni] = MFMA16(af[mi], bf[ni], acc[mi][ni]);
    }
    __syncthreads();
  }

  if (mode == 0) {
#pragma unroll
    for (int mi = 0; mi < 4; mi++) {
      const int row0 = bm + wy * 64 + mi * 16 + (lane >> 4) * 4;
#pragma unroll
      for (int ni = 0; ni < 4; ni++) {
        const int col = bn + wx * 64 + ni * 16 + (lane & 15);
        float bv = (bias != nullptr) ? bias[col] : 0.0f;
#pragma unroll
        for (int r = 0; r < 4; r++)
          C32[(size_t)(row0 + r) * Ncol + col] = acc[mi][ni][r] + bv;
      }
    }
  } else {
    // qkv scatter epilogue: dest[(frame*HH+h)*3 + qt][n][d]
#pragma unroll
    for (int mi = 0; mi < 4; mi++) {
      const int row0 = bm + wy * 64 + mi * 16 + (lane >> 4) * 4;
#pragma unroll
      for (int r = 0; r < 4; r++) {
        const int token = row0 + r;
        const int f = token / NN;
        const int n = token - f * NN;
        f16* fb = C16 + ((size_t)f * (HH * 3) * NN) * 64 + n * 64;
#pragma unroll
        for (int ni = 0; ni < 4; ni++) {
          const int col = bn + wx * 64 + ni * 16 + (lane & 15);
          const int qt = col / DD;
          const int rem = col - qt * DD;
          const int hh = rem >> 6;
          const int d = rem & 63;
          fb[(size_t)(hh * 3 + qt) * NN * 64 + d] = (f16)acc[mi][ni][r];
        }
      }
    }
  }
}

// ---------------------------------------------------------------------------
// elementwise fp32 -> fp16
// ---------------------------------------------------------------------------
__global__ __launch_bounds__(256) void conv_f32_to_f16(
    const float* __restrict__ in, f16* __restrict__ out, int n4) {
  int i = blockIdx.x * blockDim.x + threadIdx.x;
  const int stride = gridDim.x * blockDim.x;
  for (; i < n4; i += stride) {
    float4 f = ((const float4*)in)[i];
    f16x4 h;
    h[0] = (f16)f.x;
    h[1] = (f16)f.y;
    h[2] = (f16)f.z;
    h[3] = (f16)f.w;
    ((f16x4*)out)[i] = h;
  }
}

// ---------------------------------------------------------------------------
// W[K][Ncol] fp32 -> Wt[Ncol][K] fp16
// ---------------------------------------------------------------------------
__global__ __launch_bounds__(256) void transpose_f32_to_f16(
    const float* __restrict__ W, f16* __restrict__ Wt, int K, int Ncol) {
  __shared__ float tileS[32][33];
  const int k0 = blockIdx.y * 32, n0 = blockIdx.x * 32;
  const int tx = threadIdx.x & 31, ty = threadIdx.x >> 5;
#pragma unroll
  for (int i = 0; i < 4; i++)
    tileS[ty + i * 8][tx] = W[(size_t)(k0 + ty + i * 8) * Ncol + n0 + tx];
  __syncthreads();
#pragma unroll
  for (int i = 0; i < 4; i++)
    Wt[(size_t)(n0 + ty + i * 8) * K + k0 + tx] = (f16)tileS[tx][ty + i * 8];
}

// ---------------------------------------------------------------------------
// MFMA attention per (b,h,t), 512 threads (8 waves).
// qkv input layout: per (frame,h): [3][196][64] contiguous tiles.
// S=Q.K^T, p=exp(s*scale) (bounded scores, no max-subtraction), O=P.V,
// temporal V-mean folded in. Output token-major fp16 [token][768].
//
// K is NOT staged: QK B-frags read directly from global -- the 25 KB K tile
// is L1-resident and reused by all 8 waves. OOB keys (196..223) read into
// the adjacent V tile (finite garbage); their p is masked to 0 before use.
//
// LDS (40,192 B; 3 blocks/CU at __launch_bounds__(512,6)):
//   VS = V^T[64][232] f16 (stride 464 B -> 2-way banks, free)
//   PS per-wave [16][40] f16 (C/D->A layout round trip); overlaps red[]
// ---------------------------------------------------------------------------
#define VSTR 232

__global__ __launch_bounds__(512, 6) void attn_mfma(
    const f16* __restrict__ qkv, f16* __restrict__ out) {
  __shared__ f16 VS[64 * VSTR];
  __shared__ __align__(16) f16 PS[8 * 16 * 40];
  __shared__ float vmean[64];
  float* red = (float*)PS;  // red used strictly before PS (barrier between)

  const int bi = blockIdx.x;  // b*H*T + h*T + t
  const int t = bi % TT;
  const int h = (bi / TT) % HH;
  const int b = bi / (TT * HH);
  const int frame = b * TT + t;
  const int tok0 = frame * NN;

  const f16* Qb = qkv + (size_t)(frame * HH + h) * 3 * NN * 64;
  const f16* Kb = Qb + NN * 64;
  const f16* Vb = Qb + 2 * NN * 64;

  const int tid = threadIdx.x;
  const int lane = tid & 63;
  const int wave = tid >> 6;  // 0..7
  const int m = lane & 15;
  const int q = lane >> 4;

  // ---- zero VS pad cols [196,232) ----
  for (int idx = tid; idx < 64 * 9; idx += 512) {
    int d = idx / 9, c = idx % 9;
    *(f16x4*)&VS[d * VSTR + 196 + c * 4] = (f16x4){0, 0, 0, 0};
  }

  // ---- stage V^T (register-gather transpose) + v-mean partials ----
  const int vd = tid & 63;
  const int kb = tid >> 6;  // 0..7; kb==7 idle (7*28 = 196 keys exactly)
  float vpart = 0.0f;
  if (kb < 7) {
#pragma unroll
    for (int it = 0; it < 7; it++) {
      int k0 = kb * 28 + it * 4;
      f16x4 pk;
#pragma unroll
      for (int j = 0; j < 4; j++) {
        f16 v = Vb[(k0 + j) * 64 + vd];
        pk[j] = v;
        vpart += (float)v;
      }
      *(f16x4*)&VS[vd * VSTR + k0] = pk;
    }
  }
  red[tid] = vpart;
  __syncthreads();
  if (tid < 64) {
    float s = 0.0f;
#pragma unroll
    for (int g = 0; g < 8; g++) s += red[tid + 64 * g];
    vmean[tid] = s * (1.0f / (float)NN);
  }
  __syncthreads();  // red dead; PS region free for reuse

  // ---- per-wave: query tiles round-robin (13 tiles of 16 over 8 waves) ----
  f16* PSw = &PS[wave * 640];

  for (int qt = wave; qt < 13; qt += 8) {
    const int q0 = qt * 16;
    int qrow = q0 + m;
    if (qrow > NN - 1) qrow = NN - 1;  // clamp padded queries (write-guarded)
    const f16* qbase = Qb + qrow * 64;
    f16x8 aq0 = *(const f16x8*)(qbase + q * 8);
    f16x8 aq1 = *(const f16x8*)(qbase + 32 + q * 8);

    f32x4 o0 = (f32x4)0.0f, o1 = (f32x4)0.0f, o2 = (f32x4)0.0f,
          o3 = (f32x4)0.0f;
    float l[4] = {0.0f, 0.0f, 0.0f, 0.0f};

    for (int ch = 0; ch < 7; ch++) {
      const int keyA = ch * 32 + m;
      const int keyB = keyA + 16;
      // direct global B-frag reads (L1-resident tile); OOB rows land in the
      // adjacent V tile -- finite values, masked below.
      const f16* kra = Kb + keyA * 64;
      const f16* krb = Kb + keyB * 64;
      f16x8 b00 = *(const f16x8*)(kra + q * 8);
      f16x8 b01 = *(const f16x8*)(kra + 32 + q * 8);
      f16x8 b10 = *(const f16x8*)(krb + q * 8);
      f16x8 b11 = *(const f16x8*)(krb + 32 + q * 8);
      f32x4 z = (f32x4)0.0f;
      f32x4 s0 = MFMA16(aq0, b00, z);
      s0 = MFMA16(aq1, b01, s0);
      f32x4 s1 = MFMA16(aq0, b10, z);
      s1 = MFMA16(aq1, b11, s1);

      const bool v0 = keyA < NN;
      const bool v1 = keyB < NN;
#pragma unroll
      for (int r = 0; r < 4; r++) {
        float p0 = v0 ? __expf(s0[r] * 0.125f) : 0.0f;
        float p1 = v1 ? __expf(s1[r] * 0.125f) : 0.0f;
        l[r] += p0 + p1;
        PSw[(q * 4 + r) * 40 + m] = (f16)p0;
        PSw[(q * 4 + r) * 40 + 16 + m] = (f16)p1;
      }
      f16x8 pa = *(const f16x8*)&PSw[m * 40 + q * 8];
      f16x8 bv0 = *(const f16x8*)&VS[(0 * 16 + m) * VSTR + ch * 32 + q * 8];
      f16x8 bv1 = *(const f16x8*)&VS[(1 * 16 + m) * VSTR + ch * 32 + q * 8];
      f16x8 bv2 = *(const f16x8*)&VS[(2 * 16 + m) * VSTR + ch * 32 + q * 8];
      f16x8 bv3 = *(const f16x8*)&VS[(3 * 16 + m) * VSTR + ch * 32 + q * 8];
      o0 = MFMA16(pa, bv0, o0);
      o1 = MFMA16(pa, bv1, o1);
      o2 = MFMA16(pa, bv2, o2);
      o3 = MFMA16(pa, bv3, o3);
    }

    // row-sum l across the 16 lanes holding each row's columns
#pragma unroll
    for (int r = 0; r < 4; r++) {
      float s = l[r];
      s += __shfl_xor(s, 1);
      s += __shfl_xor(s, 2);
      s += __shfl_xor(s, 4);
      s += __shfl_xor(s, 8);
      l[r] = 1.0f / s;
    }

    // write O: row=q0+q*4+r (token-major), col=g*16+m
#pragma unroll
    for (int r = 0; r < 4; r++) {
      const int query = q0 + q * 4 + r;
      if (query < NN) {
        f16* orow = out + (size_t)(tok0 + query) * DD + h * HD;
        orow[m] = (f16)(o0[r] * l[r] + vmean[m]);
        orow[16 + m] = (f16)(o1[r] * l[r] + vmean[16 + m]);
        orow[32 + m] = (f16)(o2[r] * l[r] + vmean[32 + m]);
        orow[48 + m] = (f16)(o3[r] * l[r] + vmean[48 + m]);
      }
    }
  }
}

// ---------------------------------------------------------------------------
extern "C" void kernel_launch(void* const* d_in, const int* in_sizes, int n_in,
                              void* d_out, int out_size, void* d_ws,
                              size_t ws_size, hipStream_t stream) {
  (void)in_sizes;
  (void)n_in;
  (void)out_size;
  (void)ws_size;
  const float* x      = (const float*)d_in[0];
  const float* w_qkv  = (const float*)d_in[3];
  const float* w_proj = (const float*)d_in[4];
  const float* b_proj = (const float*)d_in[5];
  float* out = (float*)d_out;

  // workspace: qkvh (fp16 MM*D3, tile layout) | xh (fp16 MM*DD, reused for
  //            attn out) | wqkvT | wprojT   (~82 MB total)
  char* ws = (char*)d_ws;
  f16* qkvh = (f16*)ws;
  f16* xh = (f16*)(ws + (size_t)MM * D3 * 2);
  f16* wqkvT = xh + (size_t)MM * DD;
  f16* wprojT = wqkvT + (size_t)D3 * DD;

  conv_f32_to_f16<<<2048, 256, 0, stream>>>(x, xh, MM * DD / 4);
  transpose_f32_to_f16<<<dim3(D3 / 32, DD / 32), 256, 0, stream>>>(w_qkv,
                                                                   wqkvT, DD, D3);
  transpose_f32_to_f16<<<dim3(DD / 32, DD / 32), 256, 0, stream>>>(w_proj,
                                                                   wprojT, DD, DD);
  // 1) qkv (fp16, attention tile layout) = x @ w_qkv
  //    mTiles=98 -> mSuper=13; grid = 8*13*nTiles
  gemm_f16nt<<<8 * 13 * 18, 256, 0, stream>>>(
      xh, wqkvT, nullptr, qkvh, DD, D3, nullptr, 1, 98, 18);
  // 2) MFMA attention + temporal mean -> fp16 token-major (overwrites xh)
  attn_mfma<<<BB * HH * TT, 512, 0, stream>>>(qkvh, xh);
  // 3) out = attn @ w_proj + b_proj (fp32 out)
  gemm_f16nt<<<8 * 13 * 6, 256, 0, stream>>>(
      xh, wprojT, out, nullptr, DD, DD, b_proj, 0, 98, 6);
}